// Round 7
// baseline (2294.872 us; speedup 1.0000x reference)
//
#include <hip/hip_runtime.h>

static constexpr int   BATCH = 131072;
static constexpr int   TS    = 30;
static constexpr int   DD    = 10;
static constexpr int   HH    = 20;
static constexpr float EPSV  = 1e-5f;
static constexpr float INV_B = 1.0f / (float)BATCH;

static constexpr int NBLK = 256;   // 1 block/CU, cooperative
static constexpr int NTHR = 512;   // one batch row per thread
static constexpr int NS   = 8;     // stat accumulation slots (blockIdx&7)
static constexpr int GRPS = 8;     // arrival tree groups
static constexpr int GSZ  = NBLK / GRPS;
static constexpr int NVA  = 230;   // phase-A: 210 tri second-moments + 20 sums
static constexpr int NVB  = 40;    // phase-B: 20 sums + 20 sumsq
static constexpr int STRA = NVA * NS;      // 1840 floats / t
static constexpr int STRB = NVB * NS;      //  320 floats / t
static constexpr int NPH  = TS * 2;        // 60 phases
static constexpr int CTRW = 160;           // uints per phase: groups @ g*16, root @128, flag @144

__device__ __forceinline__ int tri(int k, int l) {  // k <= l
    return k * (41 - k) / 2 + (l - k);
}

template <int CTRL>
__device__ __forceinline__ float dpp_add(float v) {
    int x = __builtin_amdgcn_update_dpp(0, __float_as_int(v), CTRL, 0xF, 0xF, true);
    return v + __int_as_float(x);
}

__device__ __forceinline__ float rowsum16(float v) {
    v = dpp_add<0x111>(v);
    v = dpp_add<0x112>(v);
    v = dpp_add<0x114>(v);
    v = dpp_add<0x118>(v);
    return v;   // lane 15 of each 16 holds the total
}

// All cross-block movement is agent-scope ATOMICS (coherent at the fabric
// point) -> NO cache-maintenance fences anywhere in this kernel. Plain cached
// loads are used only for read-only inputs (x, weights) and LDS.
__device__ __forceinline__ unsigned armw(unsigned* p) {
    return __hip_atomic_fetch_add(p, 1u, __ATOMIC_RELAXED, __HIP_MEMORY_SCOPE_AGENT);
}
__device__ __forceinline__ unsigned apoll(unsigned* p) {
    return __hip_atomic_load(p, __ATOMIC_RELAXED, __HIP_MEMORY_SCOPE_AGENT);
}
__device__ __forceinline__ void astoref(float* p, float v) {
    __hip_atomic_store(p, v, __ATOMIC_RELAXED, __HIP_MEMORY_SCOPE_AGENT);
}
__device__ __forceinline__ float aloadf(const float* p) {
    return __hip_atomic_load(p, __ATOMIC_RELAXED, __HIP_MEMORY_SCOPE_AGENT);
}

__global__ void __launch_bounds__(NTHR, 1)
rnn_bn_kernel(const float* __restrict__ x,
              const float* __restrict__ g0, const float* __restrict__ be0,
              const float* __restrict__ W1, const float* __restrict__ b1,
              const float* __restrict__ g1, const float* __restrict__ be1,
              const float* __restrict__ W2, const float* __restrict__ b2,
              const float* __restrict__ g2, const float* __restrict__ be2,
              const float* __restrict__ W3, const float* __restrict__ b3,
              float* __restrict__ out,
              float* __restrict__ redA, float* __restrict__ redB,
              unsigned* __restrict__ ctr, float* __restrict__ pslab)
{
    __shared__ float lred[32 * NVA];
    __shared__ float sM[230];
    __shared__ float sMu[20], sCov[400], sU[400], sP[400];
    __shared__ float sW1[400], sW2[400], sW3[200], sB3[10];
    __shared__ float sA0[20], sC0[20], sA1[20], sC1[20], sA2[20], sC2[20];
    __shared__ int   role;

    const int tid     = threadIdx.x;
    const int grp     = tid >> 4;
    const bool lane15 = (tid & 15) == 15;
    const int slot    = blockIdx.x & (NS - 1);
    const int grp8    = blockIdx.x & (GRPS - 1);
    const int gt      = blockIdx.x * NTHR + tid;

    float prev[DD];
#pragma unroll
    for (int d = 0; d < DD; ++d) prev[d] = 0.0f;

    float xt[DD];
    {
        const float* px = x + (size_t)gt * TS * DD;
#pragma unroll
        for (int d = 0; d < DD; ++d) xt[d] = px[d];
    }

    for (int t = 0; t < TS; ++t) {
        // ---- stage weights (plain cached loads; read-only data, no coherence issue)
        if (tid < 400) { sW1[tid] = W1[t * 400 + tid]; sW2[tid] = W2[t * 400 + tid]; }
        if (tid < 200) sW3[tid] = W3[t * 200 + tid];
        if (tid >= 500 && tid < 510) sB3[tid - 500] = b3[t * DD + (tid - 500)];

        // ================= phase A: second moments of h0 = [x_t, prev] =========
#define H0E(i) ((i) < DD ? xt[i] : prev[(i) - DD])
        {
            int v = 0;
#pragma unroll
            for (int k = 0; k < 2 * DD; ++k) {
#pragma unroll
                for (int l = k; l < 2 * DD; ++l) {
                    float r = rowsum16(H0E(k) * H0E(l));
                    if (lane15) lred[grp * NVA + v] = r;
                    ++v;
                }
            }
#pragma unroll
            for (int k = 0; k < 2 * DD; ++k) {
                float r = rowsum16(H0E(k));
                if (lane15) lred[grp * NVA + 210 + k] = r;
            }
        }
        __syncthreads();
        if (tid < NVA) {
            float acc = 0.0f;
#pragma unroll
            for (int g = 0; g < 32; ++g) acc += lred[g * NVA + tid];
            atomicAdd(redA + (size_t)t * STRA + tid * NS + slot, acc);
        }
        __syncthreads();   // drain stat atomics (vmcnt 0) before arrival

        unsigned* cbase = ctr + (size_t)(t * 2 + 0) * CTRW;
        if (tid == 0) {
            int last = 0;
            if (armw(cbase + grp8 * 16) == (unsigned)(GSZ - 1))
                if (armw(cbase + 128) == (unsigned)(GRPS - 1)) last = 1;
            role = last;
        }
        __syncthreads();

        if (role) {
            // ---------- finalize phase A (this block only); atomic readback ----
            if (tid < NVA) {
                const float* p = redA + (size_t)t * STRA + tid * NS;
                float s = 0.0f;
#pragma unroll
                for (int i = 0; i < NS; ++i) s += aloadf(p + i);
                sM[tid] = s;
            }
            __syncthreads();
            if (tid < 20) {
                float mu  = sM[210 + tid] * INV_B;
                float var = fmaf(-mu, mu, sM[tri(tid, tid)] * INV_B);
                float a   = g0[t * 20 + tid] * rsqrtf(var + EPSV);
                sA0[tid] = a;
                sC0[tid] = fmaf(-mu, a, be0[t * 20 + tid]);
                sMu[tid] = mu;
            }
            __syncthreads();
            if (tid < 400) {
                int k = tid / 20, l = tid % 20;
                int a = k < l ? k : l, b = k < l ? l : k;
                sCov[tid] = fmaf(-sMu[k], sMu[l], sM[tri(a, b)] * INV_B);
                sU[tid]   = sW1[tid] * sA0[l];
            }
            __syncthreads();
            if (tid < 400) {
                int j = tid / 20, k = tid % 20;
                float acc = 0.0f;
#pragma unroll
                for (int l = 0; l < 20; ++l)
                    acc = fmaf(sCov[k * 20 + l], sU[j * 20 + l], acc);
                sP[tid] = acc * sU[tid];
            }
            __syncthreads();
            if (tid < 20) {
                const int j = tid;
                float var1 = 0.0f, m1 = 0.0f;
#pragma unroll
                for (int k = 0; k < 20; ++k) {
                    var1 += sP[j * 20 + k];
                    m1    = fmaf(sU[j * 20 + k], sMu[k], m1);
                    m1    = fmaf(sW1[j * 20 + k], sC0[k], m1);
                }
                float a1 = g1[t * 20 + j] * rsqrtf(var1 + EPSV);
                sA1[j] = a1;
                sC1[j] = fmaf(-m1, a1, be1[t * 20 + j]);
            }
            __syncthreads();
            // publish A0,C0,A1,C1 (80 floats), then flag (after vmcnt drain)
            if (tid < 80) {
                float v = tid < 20 ? sA0[tid] : tid < 40 ? sC0[tid - 20]
                        : tid < 60 ? sA1[tid - 40] : sC1[tid - 60];
                astoref(pslab + (size_t)(t * 2 + 0) * 128 + tid, v);
            }
            __syncthreads();   // publishes globally visible before flag
            if (tid == 0) __hip_atomic_store(cbase + 144, 1u, __ATOMIC_RELAXED,
                                             __HIP_MEMORY_SCOPE_AGENT);
        } else {
            if (tid == 0)
                while (apoll(cbase + 144) == 0) __builtin_amdgcn_s_sleep(2);
            __syncthreads();
            if (tid < 80) {
                float v = aloadf(pslab + (size_t)(t * 2 + 0) * 128 + tid);
                if      (tid < 20) sA0[tid]      = v;
                else if (tid < 40) sC0[tid - 20] = v;
                else if (tid < 60) sA1[tid - 40] = v;
                else               sC1[tid - 60] = v;
            }
        }
        __syncthreads();

        // ================= forward layers 1,2 ===================================
        float hn[20];
#pragma unroll
        for (int k = 0; k < 20; ++k) hn[k] = fmaf(H0E(k), sA0[k], sC0[k]);
#undef H0E

        float h1[20];
#pragma unroll
        for (int j = 0; j < 20; ++j) {
            float y = 0.0f;
#pragma unroll
            for (int k = 0; k < 20; ++k) y = fmaf(sW1[j * 20 + k], hn[k], y);
            h1[j] = fmaxf(fmaf(y, sA1[j], sC1[j]), 0.0f);
        }

        float y2[20];
#pragma unroll
        for (int j = 0; j < 20; ++j) {
            float y = 0.0f;
#pragma unroll
            for (int k = 0; k < 20; ++k) y = fmaf(sW2[j * 20 + k], h1[k], y);
            y2[j] = y;   // b2 cancels in BN2
        }

        // ================= phase B: stats of y2 =================================
        {
#pragma unroll
            for (int j = 0; j < 20; ++j) {
                float r = rowsum16(y2[j]);
                if (lane15) lred[grp * NVA + j] = r;
            }
#pragma unroll
            for (int j = 0; j < 20; ++j) {
                float r = rowsum16(y2[j] * y2[j]);
                if (lane15) lred[grp * NVA + 20 + j] = r;
            }
        }
        __syncthreads();
        if (tid < NVB) {
            float acc = 0.0f;
#pragma unroll
            for (int g = 0; g < 32; ++g) acc += lred[g * NVA + tid];
            atomicAdd(redB + (size_t)t * STRB + tid * NS + slot, acc);
        }

        // prefetch x_{t+1} (registers; overlaps barrier wait)
        float xn[DD];
        if (t + 1 < TS) {
            const float* px = x + ((size_t)gt * TS + (t + 1)) * DD;
#pragma unroll
            for (int d = 0; d < DD; ++d) xn[d] = px[d];
        }
        __syncthreads();   // drain stat atomics before arrival

        cbase = ctr + (size_t)(t * 2 + 1) * CTRW;
        if (tid == 0) {
            int last = 0;
            if (armw(cbase + grp8 * 16) == (unsigned)(GSZ - 1))
                if (armw(cbase + 128) == (unsigned)(GRPS - 1)) last = 1;
            role = last;
        }
        __syncthreads();

        if (role) {
            if (tid < NVB) {
                const float* p = redB + (size_t)t * STRB + tid * NS;
                float s = 0.0f;
#pragma unroll
                for (int i = 0; i < NS; ++i) s += aloadf(p + i);
                sM[tid] = s;
            }
            __syncthreads();
            if (tid < 20) {
                float m   = sM[tid] * INV_B;
                float var = fmaf(-m, m, sM[20 + tid] * INV_B);
                float a   = g2[t * 20 + tid] * rsqrtf(var + EPSV);
                sA2[tid] = a;
                sC2[tid] = fmaf(-m, a, be2[t * 20 + tid]);
            }
            __syncthreads();
            if (tid < 40) {
                float v = tid < 20 ? sA2[tid] : sC2[tid - 20];
                astoref(pslab + (size_t)(t * 2 + 1) * 128 + tid, v);
            }
            __syncthreads();
            if (tid == 0) __hip_atomic_store(cbase + 144, 1u, __ATOMIC_RELAXED,
                                             __HIP_MEMORY_SCOPE_AGENT);
        } else {
            if (tid == 0)
                while (apoll(cbase + 144) == 0) __builtin_amdgcn_s_sleep(2);
            __syncthreads();
            if (tid < 40) {
                float v = aloadf(pslab + (size_t)(t * 2 + 1) * 128 + tid);
                if (tid < 20) sA2[tid] = v; else sC2[tid - 20] = v;
            }
        }
        __syncthreads();

        // ================= layer 3 + output =====================================
        float h2[20];
#pragma unroll
        for (int j = 0; j < 20; ++j)
            h2[j] = fmaxf(fmaf(y2[j], sA2[j], sC2[j]), 0.0f);

        {
            float* po = out + ((size_t)gt * TS + t) * DD;
#pragma unroll
            for (int d = 0; d < DD; ++d) {
                float a = sB3[d];
#pragma unroll
                for (int j = 0; j < 20; ++j)
                    a = fmaf(sW3[d * 20 + j], h2[j], a);
                po[d] = a;
                prev[d] = a;
            }
        }
        if (t + 1 < TS) {
#pragma unroll
            for (int d = 0; d < DD; ++d) xt[d] = xn[d];
        }
        __syncthreads();   // protect LDS before next step's staging
    }
}

extern "C" void kernel_launch(void* const* d_in, const int* in_sizes, int n_in,
                              void* d_out, int out_size, void* d_ws, size_t ws_size,
                              hipStream_t stream) {
    const float* x   = (const float*)d_in[0];
    const float* g0  = (const float*)d_in[1];
    const float* be0 = (const float*)d_in[2];
    const float* W1  = (const float*)d_in[3];
    const float* b1  = (const float*)d_in[4];
    const float* g1  = (const float*)d_in[5];
    const float* be1 = (const float*)d_in[6];
    const float* W2  = (const float*)d_in[7];
    const float* b2  = (const float*)d_in[8];
    const float* g2  = (const float*)d_in[9];
    const float* be2 = (const float*)d_in[10];
    const float* W3  = (const float*)d_in[11];
    const float* b3  = (const float*)d_in[12];
    float* out = (float*)d_out;

    const size_t redA_f  = (size_t)TS * STRA;    // 55200
    const size_t redB_f  = (size_t)TS * STRB;    //  9600
    const size_t ctr_u   = (size_t)NPH * CTRW;   //  9600 uints
    const size_t pslab_f = (size_t)NPH * 128;    //  7680

    float*    redA  = (float*)d_ws;
    float*    redB  = redA + redA_f;
    unsigned* ctr   = (unsigned*)(redB + redB_f);
    float*    pslab = (float*)(ctr + ctr_u);

    const size_t total_bytes = (redA_f + redB_f + pslab_f) * 4 + ctr_u * 4;
    hipMemsetAsync(d_ws, 0, total_bytes, stream);

    void* args[] = { &x, &g0, &be0, &W1, &b1, &g1, &be1, &W2, &b2, &g2, &be2,
                     &W3, &b3, &out, &redA, &redB, &ctr, &pslab };
    hipLaunchCooperativeKernel((const void*)rnn_bn_kernel, dim3(NBLK), dim3(NTHR),
                               args, 0, stream);
}

// Round 9
// 1644.317 us; speedup vs baseline: 1.3956x; 1.3956x over previous
//
#include <hip/hip_runtime.h>

static constexpr int   BATCH = 131072;
static constexpr int   TS    = 30;
static constexpr int   DD    = 10;
static constexpr int   HH    = 20;
static constexpr float EPSV  = 1e-5f;
static constexpr float INV_B = 1.0f / (float)BATCH;

static constexpr int NTHR = 256;
static constexpr int NBLK = BATCH / NTHR;   // 512 blocks, 1 row/thread
static constexpr int NS   = 8;              // stat slot spread (blockIdx&7)
static constexpr int NVA  = 230;            // 210 tri second-moments + 20 sums
static constexpr int NVB  = 40;             // 20 sums + 20 sumsq
static constexpr int STRA = NVA * NS;       // 1840 floats per t
static constexpr int STRB = NVB * NS;       //  320 floats per t

__device__ __forceinline__ int tri(int k, int l) {  // k <= l
    return k * (41 - k) / 2 + (l - k);
}

template <int CTRL>
__device__ __forceinline__ float dpp_add(float v) {
    int x = __builtin_amdgcn_update_dpp(0, __float_as_int(v), CTRL, 0xF, 0xF, true);
    return v + __int_as_float(x);
}

__device__ __forceinline__ float rowsum16(float v) {
    v = dpp_add<0x111>(v);
    v = dpp_add<0x112>(v);
    v = dpp_add<0x114>(v);
    v = dpp_add<0x118>(v);
    return v;   // lane 15 of each 16 holds the total
}

// ---------------- forward kernel: params(analytic BN0/BN1) + layers1,2 + y2 stats
__global__ void __launch_bounds__(NTHR)
k_fwd(const float* __restrict__ x, const float* __restrict__ prevg,
      float* __restrict__ y2g,
      const float* __restrict__ W1, const float* __restrict__ W2,
      const float* __restrict__ g0, const float* __restrict__ be0,
      const float* __restrict__ g1, const float* __restrict__ be1,
      const float* __restrict__ redA, float* __restrict__ redB, int t)
{
    __shared__ float sW1[400], sW2[400];
    __shared__ float sM[230], sMu[20], sCov[400], sU[400], sP[400];
    __shared__ float sA0[20], sC0[20], sA1[20], sC1[20];
    __shared__ float lred[16 * NVB];

    const int tid     = threadIdx.x;
    const int grp     = tid >> 4;
    const bool lane15 = (tid & 15) == 15;
    const int row     = blockIdx.x * NTHR + tid;

    // ---- readback stats (plain loads; cross-kernel visibility via stream order)
    if (tid < NVA) {
        const float* p = redA + (size_t)t * STRA + tid * NS;
        float s = 0.0f;
#pragma unroll
        for (int i = 0; i < NS; ++i) s += p[i];
        sM[tid] = s;
    }
    for (int i = tid; i < 400; i += NTHR) { sW1[i] = W1[t * 400 + i]; sW2[i] = W2[t * 400 + i]; }
    __syncthreads();

    // ---- BN0 params
    if (tid < 20) {
        float mu  = sM[210 + tid] * INV_B;
        float var = fmaf(-mu, mu, sM[tri(tid, tid)] * INV_B);
        float a   = g0[t * 20 + tid] * rsqrtf(var + EPSV);
        sA0[tid] = a;
        sC0[tid] = fmaf(-mu, a, be0[t * 20 + tid]);
        sMu[tid] = mu;
    }
    __syncthreads();

    // ---- covariance + U = W1 ∘ A0
    for (int i = tid; i < 400; i += NTHR) {
        int k = i / 20, l = i % 20;
        int a = k < l ? k : l, b = k < l ? l : k;
        sCov[i] = fmaf(-sMu[k], sMu[l], sM[tri(a, b)] * INV_B);
        sU[i]   = sW1[i] * sA0[l];
    }
    __syncthreads();

    // ---- P[j,k] = U[j,k] * (Cov[k,:] · U[j,:])
    for (int i = tid; i < 400; i += NTHR) {
        int j = i / 20, k = i % 20;
        float acc = 0.0f;
#pragma unroll
        for (int l = 0; l < 20; ++l)
            acc = fmaf(sCov[k * 20 + l], sU[j * 20 + l], acc);
        sP[i] = acc * sU[i];
    }
    __syncthreads();

    // ---- analytic BN1 params (b1 cancels in BN)
    if (tid < 20) {
        float var1 = 0.0f, m1 = 0.0f;
#pragma unroll
        for (int k = 0; k < 20; ++k) {
            var1 += sP[tid * 20 + k];
            m1    = fmaf(sU[tid * 20 + k], sMu[k], m1);
            m1    = fmaf(sW1[tid * 20 + k], sC0[k], m1);
        }
        float a1 = g1[t * 20 + tid] * rsqrtf(var1 + EPSV);
        sA1[tid] = a1;
        sC1[tid] = fmaf(-m1, a1, be1[t * 20 + tid]);
    }
    __syncthreads();

    // ---- per-row forward
    float xv[DD], pv[DD];
    {
        const float2* px = reinterpret_cast<const float2*>(x + (size_t)row * TS * DD + t * DD);
#pragma unroll
        for (int i = 0; i < 5; ++i) { float2 v = px[i]; xv[2 * i] = v.x; xv[2 * i + 1] = v.y; }
    }
#pragma unroll
    for (int d = 0; d < DD; ++d) pv[d] = prevg[(size_t)d * BATCH + row];

    float hn[20];
#pragma unroll
    for (int k = 0; k < 10; ++k) hn[k]      = fmaf(xv[k], sA0[k],      sC0[k]);
#pragma unroll
    for (int k = 0; k < 10; ++k) hn[10 + k] = fmaf(pv[k], sA0[10 + k], sC0[10 + k]);

    float h1[20];
#pragma unroll
    for (int j = 0; j < 20; ++j) {
        float y = 0.0f;
#pragma unroll
        for (int k = 0; k < 20; ++k) y = fmaf(sW1[j * 20 + k], hn[k], y);
        h1[j] = fmaxf(fmaf(y, sA1[j], sC1[j]), 0.0f);
    }
    float y2[20];
#pragma unroll
    for (int j = 0; j < 20; ++j) {
        float y = 0.0f;
#pragma unroll
        for (int k = 0; k < 20; ++k) y = fmaf(sW2[j * 20 + k], h1[k], y);
        y2[j] = y;   // b2 cancels in BN2
#pragma unroll
        for (int dummy = 0; dummy < 1; ++dummy) y2g[(size_t)j * BATCH + row] = y;
    }

    // ---- y2 stats
#pragma unroll
    for (int j = 0; j < 20; ++j) {
        float r = rowsum16(y2[j]);
        if (lane15) lred[grp * NVB + j] = r;
    }
#pragma unroll
    for (int j = 0; j < 20; ++j) {
        float r = rowsum16(y2[j] * y2[j]);
        if (lane15) lred[grp * NVB + 20 + j] = r;
    }
    __syncthreads();
    if (tid < NVB) {
        float acc = 0.0f;
#pragma unroll
        for (int g = 0; g < 16; ++g) acc += lred[g * NVB + tid];
        atomicAdd(redB + (size_t)t * STRB + tid * NS + (blockIdx.x & (NS - 1)), acc);
    }
}

// ---------------- out kernel: finish step t-1 (BN2+layer3+out+prev), begin step t (statsA)
template <bool HF, bool HB>
__global__ void __launch_bounds__(NTHR)
k_out(const float* __restrict__ x, float* __restrict__ prevg,
      const float* __restrict__ y2g, float* __restrict__ outg,
      const float* __restrict__ W3, const float* __restrict__ b3,
      const float* __restrict__ g2, const float* __restrict__ be2,
      const float* __restrict__ redB, float* __restrict__ redA, int t)
{
    __shared__ float sW3[200], sB3[10], sA2[20], sC2[20], sSB[40];
    __shared__ float lred[16 * NVA];

    const int tid     = threadIdx.x;
    const int grp     = tid >> 4;
    const bool lane15 = (tid & 15) == 15;
    const int row     = blockIdx.x * NTHR + tid;

    float pv[DD];
    if constexpr (HF) {
        const int tf = t - 1;
        if (tid < NVB) {
            const float* p = redB + (size_t)tf * STRB + tid * NS;
            float s = 0.0f;
#pragma unroll
            for (int i = 0; i < NS; ++i) s += p[i];
            sSB[tid] = s;
        }
        if (tid < 200) sW3[tid] = W3[tf * 200 + tid];
        if (tid >= 200 && tid < 210) sB3[tid - 200] = b3[tf * DD + (tid - 200)];
        __syncthreads();
        if (tid < 20) {
            float m   = sSB[tid] * INV_B;
            float var = fmaf(-m, m, sSB[20 + tid] * INV_B);
            float a   = g2[tf * 20 + tid] * rsqrtf(var + EPSV);
            sA2[tid] = a;
            sC2[tid] = fmaf(-m, a, be2[tf * 20 + tid]);
        }
        __syncthreads();

        float h2[20];
#pragma unroll
        for (int j = 0; j < 20; ++j)
            h2[j] = fmaxf(fmaf(y2g[(size_t)j * BATCH + row], sA2[j], sC2[j]), 0.0f);

        float ov[DD];
#pragma unroll
        for (int d = 0; d < DD; ++d) {
            float a = sB3[d];
#pragma unroll
            for (int j = 0; j < 20; ++j)
                a = fmaf(sW3[d * 20 + j], h2[j], a);
            ov[d] = a;
            pv[d] = a;
        }
        {
            float2* po = reinterpret_cast<float2*>(outg + (size_t)row * TS * DD + tf * DD);
#pragma unroll
            for (int i = 0; i < 5; ++i) po[i] = make_float2(ov[2 * i], ov[2 * i + 1]);
        }
#pragma unroll
        for (int d = 0; d < DD; ++d) prevg[(size_t)d * BATCH + row] = pv[d];
    } else {
#pragma unroll
        for (int d = 0; d < DD; ++d) { pv[d] = 0.0f; prevg[(size_t)d * BATCH + row] = 0.0f; }
    }

    if constexpr (HB) {
        float xv[DD];
        {
            const float2* px = reinterpret_cast<const float2*>(x + (size_t)row * TS * DD + t * DD);
#pragma unroll
            for (int i = 0; i < 5; ++i) { float2 v = px[i]; xv[2 * i] = v.x; xv[2 * i + 1] = v.y; }
        }
#define H0(i) ((i) < DD ? xv[i] : pv[(i) - DD])
        {
            int v = 0;
#pragma unroll
            for (int k = 0; k < 2 * DD; ++k) {
#pragma unroll
                for (int l = k; l < 2 * DD; ++l) {
                    float r = rowsum16(H0(k) * H0(l));
                    if (lane15) lred[grp * NVA + v] = r;
                    ++v;
                }
            }
#pragma unroll
            for (int k = 0; k < 2 * DD; ++k) {
                float r = rowsum16(H0(k));
                if (lane15) lred[grp * NVA + 210 + k] = r;
            }
        }
#undef H0
        __syncthreads();
        if (tid < NVA) {
            float acc = 0.0f;
#pragma unroll
            for (int g = 0; g < 16; ++g) acc += lred[g * NVA + tid];
            atomicAdd(redA + (size_t)t * STRA + tid * NS + (blockIdx.x & (NS - 1)), acc);
        }
    }
}

extern "C" void kernel_launch(void* const* d_in, const int* in_sizes, int n_in,
                              void* d_out, int out_size, void* d_ws, size_t ws_size,
                              hipStream_t stream) {
    const float* x   = (const float*)d_in[0];
    const float* g0  = (const float*)d_in[1];
    const float* be0 = (const float*)d_in[2];
    const float* W1  = (const float*)d_in[3];
    const float* b1  = (const float*)d_in[4];   (void)b1;  // cancels in BN1
    const float* g1  = (const float*)d_in[5];
    const float* be1 = (const float*)d_in[6];
    const float* W2  = (const float*)d_in[7];
    const float* b2  = (const float*)d_in[8];   (void)b2;  // cancels in BN2
    const float* g2  = (const float*)d_in[9];
    const float* be2 = (const float*)d_in[10];
    const float* W3  = (const float*)d_in[11];
    const float* b3  = (const float*)d_in[12];
    float* out = (float*)d_out;

    const size_t redA_f = (size_t)TS * STRA;    // 55200
    const size_t redB_f = (size_t)TS * STRB;    //  9600
    float* redA  = (float*)d_ws;
    float* redB  = redA + redA_f;
    float* prevg = redB + redB_f;                     // [DD][BATCH]   5.2 MB
    float* y2g   = prevg + (size_t)DD * BATCH;        // [HH][BATCH]  10.5 MB

    // zero only the stat accumulators; prevg is fully written by k_out before use
    hipMemsetAsync(d_ws, 0, (redA_f + redB_f) * sizeof(float), stream);

    // t=0: begin only (prev := 0)
    k_out<false, true><<<NBLK, NTHR, 0, stream>>>(x, prevg, y2g, out, W3, b3, g2, be2,
                                                  redB, redA, 0);
    for (int t = 0; t < TS; ++t) {
        k_fwd<<<NBLK, NTHR, 0, stream>>>(x, prevg, y2g, W1, W2, g0, be0, g1, be1,
                                         redA, redB, t);
        if (t + 1 < TS)
            k_out<true, true><<<NBLK, NTHR, 0, stream>>>(x, prevg, y2g, out, W3, b3,
                                                         g2, be2, redB, redA, t + 1);
        else
            k_out<true, false><<<NBLK, NTHR, 0, stream>>>(x, prevg, y2g, out, W3, b3,
                                                          g2, be2, redB, redA, t + 1);
    }
}